// Round 15
// baseline (99.109 us; speedup 1.0000x reference)
//
#include <hip/hip_runtime.h>
#include <math.h>

#define N_NODES 81
#define N_EDGES 1620
#define IN_DIM 10
#define HIDDEN 8192
#define ACTIONS 729
#define NT_CH 92   // k-chunks >= this streamed non-temporally (L3 retention)

// ---- K1: 648 blocks = 81 nodes x 8 col-tiles. Each block: edge agg -> yr,
//      then partial LN sums (S, S2) over its 1024-col tile -> stats_part.
//      Block 0 zeroes logits+ctr; blocks 1..8 zero g2a.
__global__ __launch_bounds__(256) void stats_kernel(const float* __restrict__ x,
                                                    const int* __restrict__ ei,
                                                    const float* __restrict__ Wg,
                                                    const float* __restrict__ bg,
                                                    float* __restrict__ yr_all,
                                                    float* __restrict__ stats_part,
                                                    float* __restrict__ logits,
                                                    unsigned* __restrict__ ctr,
                                                    float* __restrict__ g2a) {
    const int bid = blockIdx.x;
    const int n = bid >> 3;
    const int jt = bid & 7;
    const int t = threadIdx.x;
    __shared__ float deg[N_NODES];
    __shared__ float yr[IN_DIM];
    __shared__ float red[8];

    if (t < N_NODES) deg[t] = 1.0f;           // self-loop
    if (t < IN_DIM) yr[t] = 0.0f;
    __syncthreads();
    for (int e = t; e < N_EDGES; e += 256) atomicAdd(&deg[ei[N_EDGES + e]], 1.0f);
    __syncthreads();
    if (t < N_NODES) deg[t] = rsqrtf(deg[t]); // deg >= 1 always
    __syncthreads();
    const float dn = deg[n];
    for (int e = t; e < N_EDGES; e += 256) {
        if (ei[N_EDGES + e] == n) {
            int s = ei[e];
            float nrm = deg[s] * dn;
            #pragma unroll
            for (int c = 0; c < IN_DIM; ++c) atomicAdd(&yr[c], nrm * x[s * IN_DIM + c]);
        }
    }
    if (t == 0) {
        float nrm = dn * dn;
        #pragma unroll
        for (int c = 0; c < IN_DIM; ++c) atomicAdd(&yr[c], nrm * x[n * IN_DIM + c]);
    }
    __syncthreads();
    if (jt == 0 && t < IN_DIM) yr_all[n * IN_DIM + t] = yr[t];
    if (bid == 0) {
        for (int a = t; a < ACTIONS; a += 256) logits[a] = 0.f;
        if (t == 0) *ctr = 0u;
    }
    if (bid >= 1 && bid <= 8) {
        const int base = (bid - 1) * 1024;
        #pragma unroll
        for (int k = 0; k < 4; ++k) g2a[base + t + k * 256] = 0.f;
    }

    // LN partial sums over this block's 1024-col tile (1 float4 per thread)
    const float4* Wg4 = (const float4*)Wg;    // [IN_DIM][2048]
    const float4* bg4 = (const float4*)bg;
    const int j4 = jt * 256 + t;
    float4 h = bg4[j4];
    #pragma unroll
    for (int c = 0; c < IN_DIM; ++c) {
        float4 w = Wg4[c * (HIDDEN / 4) + j4];
        float yc = yr[c];
        h.x = fmaf(yc, w.x, h.x);
        h.y = fmaf(yc, w.y, h.y);
        h.z = fmaf(yc, w.z, h.z);
        h.w = fmaf(yc, w.w, h.w);
    }
    h.x = fmaxf(h.x, 0.f); h.y = fmaxf(h.y, 0.f);
    h.z = fmaxf(h.z, 0.f); h.w = fmaxf(h.w, 0.f);
    float s  = h.x + h.y + h.z + h.w;
    float s2 = h.x * h.x + h.y * h.y + h.z * h.z + h.w * h.w;
    #pragma unroll
    for (int off = 32; off > 0; off >>= 1) { s += __shfl_xor(s, off); s2 += __shfl_xor(s2, off); }
    int wave = t >> 6, lane = t & 63;
    if (lane == 0) { red[wave] = s; red[4 + wave] = s2; }
    __syncthreads();
    if (t == 0) {
        stats_part[n * 16 + jt * 2]     = red[0] + red[1] + red[2] + red[3];
        stats_part[n * 16 + jt * 2 + 1] = red[4] + red[5] + red[6] + red[7];
    }
}

// ---- K2: gemv1. Grid (128, 8): ch = blockIdx.x (XCD = ch%8). Preamble
//      rebuilds mu/inv from stats_part + recomputes the 64-row g slice,
//      then streams W1 (NT tail) and atomicAdds float4 column sums into g2a.
__global__ __launch_bounds__(256) void gemv1_kernel(const float* __restrict__ Wg,
                                                    const float* __restrict__ bg,
                                                    const float* __restrict__ lng,
                                                    const float* __restrict__ lnb,
                                                    const float* __restrict__ yr_all,
                                                    const float* __restrict__ stats_part,
                                                    const float* __restrict__ W1,
                                                    float* __restrict__ g2a) {
    const int ch = blockIdx.x;     // 0..127 k chunk (64 rows)
    const int ct = blockIdx.y;     // 0..7   col tile (1024 cols)
    const int row0 = ch * 64;
    const int t = threadIdx.x;

    __shared__ float syr[N_NODES * IN_DIM];   // 810
    __shared__ float spart[N_NODES * 16];     // 1296
    __shared__ float sstat[2 * N_NODES];      // 162
    __shared__ float sw[IN_DIM][64];
    __shared__ float gred[4][64];
    __shared__ float gl[64];

    for (int i = t; i < N_NODES * IN_DIM; i += 256) syr[i] = yr_all[i];
    for (int i = t; i < N_NODES * 16; i += 256) spart[i] = stats_part[i];
    if (t < 64) {
        #pragma unroll
        for (int c = 0; c < IN_DIM; ++c) sw[c][t] = Wg[c * HIDDEN + row0 + t];
    }
    __syncthreads();
    if (t < N_NODES) {
        float S = 0.f, S2 = 0.f;
        #pragma unroll
        for (int j = 0; j < 8; ++j) { S += spart[t * 16 + 2 * j]; S2 += spart[t * 16 + 2 * j + 1]; }
        float mu = S * (1.f / HIDDEN);
        float var = S2 * (1.f / HIDDEN) - mu * mu;
        sstat[2 * t]     = mu;
        sstat[2 * t + 1] = rsqrtf(var + 1e-5f);
    }
    __syncthreads();

    {
        const int r = t & 63, grp = t >> 6;
        const float bgv = bg[row0 + r];
        float acc = 0.f;
        for (int n = grp; n < N_NODES; n += 4) {
            float h = bgv;
            #pragma unroll
            for (int c = 0; c < IN_DIM; ++c) h = fmaf(syr[n * IN_DIM + c], sw[c][r], h);
            h = fmaxf(h, 0.f);
            acc += (h - sstat[2 * n]) * sstat[2 * n + 1];
        }
        gred[grp][r] = acc;
    }
    __syncthreads();
    if (t < 64)
        gl[t] = (gred[0][t] + gred[1][t] + gred[2][t] + gred[3][t]) * lng[row0 + t]
                + (float)N_NODES * lnb[row0 + t];
    __syncthreads();

    float4 acc = make_float4(0.f, 0.f, 0.f, 0.f);
    const float* pbase = W1 + (size_t)row0 * HIDDEN + ct * 1024 + t * 4;
    if (ch >= NT_CH) {
        #pragma unroll 8
        for (int i = 0; i < 64; ++i) {
            const float* q = pbase + (size_t)i * HIDDEN;
            float4 w;
            w.x = __builtin_nontemporal_load(q);
            w.y = __builtin_nontemporal_load(q + 1);
            w.z = __builtin_nontemporal_load(q + 2);
            w.w = __builtin_nontemporal_load(q + 3);
            float gi = gl[i];
            acc.x = fmaf(gi, w.x, acc.x);
            acc.y = fmaf(gi, w.y, acc.y);
            acc.z = fmaf(gi, w.z, acc.z);
            acc.w = fmaf(gi, w.w, acc.w);
        }
    } else {
        const float4* p = (const float4*)pbase;
        #pragma unroll 8
        for (int i = 0; i < 64; ++i) {
            float4 w = p[(size_t)i * (HIDDEN / 4)];
            float gi = gl[i];
            acc.x = fmaf(gi, w.x, acc.x);
            acc.y = fmaf(gi, w.y, acc.y);
            acc.z = fmaf(gi, w.z, acc.z);
            acc.w = fmaf(gi, w.w, acc.w);
        }
    }
    float* q0 = g2a + ct * 1024 + t * 4;
    atomicAdd(q0 + 0, acc.x);
    atomicAdd(q0 + 1, acc.y);
    atomicAdd(q0 + 2, acc.z);
    atomicAdd(q0 + 3, acc.w);
}

// ---- K3: gemv2 + fused log-softmax via atomic-only semaphore (no fences).
//      256 blocks x 256. g2 slice read directly from g2a (no reduce).
__global__ __launch_bounds__(256) void gemv2_lsm_kernel(const float* __restrict__ g2a,
                                                        const float* __restrict__ b1,
                                                        const float* __restrict__ W2,
                                                        const float* __restrict__ b2,
                                                        float* __restrict__ logits,
                                                        unsigned* __restrict__ counter,
                                                        float* __restrict__ out) {
    const int ch = blockIdx.x;     // 0..255, 32 rows each
    const int row0 = ch * 32;
    const int t = threadIdx.x;
    __shared__ float gl[32];
    __shared__ float red[8];
    __shared__ int isLast;

    if (t < 32) gl[t] = fmaxf(g2a[row0 + t] + b1[row0 + t], 0.f);
    __syncthreads();

    float s0 = 0.f, s1 = 0.f, s2v = 0.f;
    const bool has2 = (t + 512) < ACTIONS;
    #pragma unroll 4
    for (int i = 0; i < 32; ++i) {
        float gi = gl[i];
        const float* r = W2 + (size_t)(row0 + i) * ACTIONS;
        s0 = fmaf(gi, r[t], s0);
        s1 = fmaf(gi, r[t + 256], s1);
        if (has2) s2v = fmaf(gi, r[t + 512], s2v);
    }
    atomicAdd(&logits[t], s0);
    atomicAdd(&logits[t + 256], s1);
    if (has2) atomicAdd(&logits[t + 512], s2v);

    asm volatile("s_waitcnt vmcnt(0)" ::: "memory");
    __syncthreads();
    if (t == 0) isLast = (atomicAdd(counter, 1u) == 255u) ? 1 : 0;
    __syncthreads();

    if (isLast) {
        float l0 = __hip_atomic_load(&logits[t], __ATOMIC_RELAXED,
                                     __HIP_MEMORY_SCOPE_AGENT) + b2[t];
        float l1 = __hip_atomic_load(&logits[t + 256], __ATOMIC_RELAXED,
                                     __HIP_MEMORY_SCOPE_AGENT) + b2[t + 256];
        float l2 = has2 ? (__hip_atomic_load(&logits[t + 512], __ATOMIC_RELAXED,
                                             __HIP_MEMORY_SCOPE_AGENT) + b2[t + 512])
                        : -INFINITY;
        float m = fmaxf(fmaxf(l0, l1), l2);
        #pragma unroll
        for (int off = 32; off > 0; off >>= 1) m = fmaxf(m, __shfl_xor(m, off));
        if ((t & 63) == 0) red[t >> 6] = m;
        __syncthreads();
        float M = fmaxf(fmaxf(red[0], red[1]), fmaxf(red[2], red[3]));
        __syncthreads();
        float e = __expf(l0 - M) + __expf(l1 - M) + (has2 ? __expf(l2 - M) : 0.f);
        #pragma unroll
        for (int off = 32; off > 0; off >>= 1) e += __shfl_xor(e, off);
        if ((t & 63) == 0) red[t >> 6] = e;
        __syncthreads();
        float Se = red[0] + red[1] + red[2] + red[3];
        float L = logf(Se);
        out[t] = l0 - M - L;
        out[t + 256] = l1 - M - L;
        if (has2) out[t + 512] = l2 - M - L;
    }
}

extern "C" void kernel_launch(void* const* d_in, const int* in_sizes, int n_in,
                              void* d_out, int out_size, void* d_ws, size_t ws_size,
                              hipStream_t stream) {
    const float* x    = (const float*)d_in[0];
    const int*   ei   = (const int*)  d_in[1];
    const float* Wg   = (const float*)d_in[2];
    const float* bg   = (const float*)d_in[3];
    const float* lng  = (const float*)d_in[4];
    const float* lnb  = (const float*)d_in[5];
    const float* W1   = (const float*)d_in[6];
    const float* b1   = (const float*)d_in[7];
    const float* W2   = (const float*)d_in[8];
    const float* b2   = (const float*)d_in[9];
    float* out = (float*)d_out;

    float* ws = (float*)d_ws;
    float* logits     = ws;                      // 1024 (729 used)
    unsigned* counter = (unsigned*)(ws + 1024);  // 1 (padded to 64)
    float* stats_part = ws + 1088;               // 1296
    float* yr_all     = ws + 2384;               // 810
    float* g2a        = ws + 4096;               // 8192 (16B aligned)

    stats_kernel<<<N_NODES * 8, 256, 0, stream>>>(x, ei, Wg, bg, yr_all, stats_part,
                                                  logits, counter, g2a);
    gemv1_kernel<<<dim3(128, 8), 256, 0, stream>>>(Wg, bg, lng, lnb, yr_all,
                                                   stats_part, W1, g2a);
    gemv2_lsm_kernel<<<256, 256, 0, stream>>>(g2a, b1, W2, b2, logits, counter, out);
}

// Round 16
// 93.263 us; speedup vs baseline: 1.0627x; 1.0627x over previous
//
#include <hip/hip_runtime.h>
#include <math.h>

#define N_NODES 81
#define N_EDGES 1620
#define IN_DIM 10
#define HIDDEN 8192
#define ACTIONS 729
#define NT_CH 92   // k-chunks >= this streamed non-temporally (L3 retention)

// ---- K1: 81 blocks. Edge agg -> yr; h = relu(yr@Wg+bg); LN stats in-block;
//      write hn[n][j] = lng[j]*(h-mu)*inv  (2.6 MB, consumed by K2 preamble).
//      Block 0 zeroes logits + counter.
__global__ __launch_bounds__(256) void k1_kernel(const float* __restrict__ x,
                                                 const int* __restrict__ ei,
                                                 const float* __restrict__ Wg,
                                                 const float* __restrict__ bg,
                                                 const float* __restrict__ lng,
                                                 float* __restrict__ hn,
                                                 float* __restrict__ logits,
                                                 unsigned* __restrict__ counter) {
    const int n = blockIdx.x;
    const int t = threadIdx.x;
    __shared__ float deg[N_NODES];
    __shared__ float yr[IN_DIM];
    __shared__ float red[8];

    if (t < N_NODES) deg[t] = 1.0f;           // self-loop
    if (t < IN_DIM) yr[t] = 0.0f;
    __syncthreads();
    for (int e = t; e < N_EDGES; e += 256) atomicAdd(&deg[ei[N_EDGES + e]], 1.0f);
    __syncthreads();
    if (t < N_NODES) deg[t] = rsqrtf(deg[t]); // deg >= 1 always
    __syncthreads();
    const float dn = deg[n];
    for (int e = t; e < N_EDGES; e += 256) {
        if (ei[N_EDGES + e] == n) {
            int s = ei[e];
            float nrm = deg[s] * dn;
            #pragma unroll
            for (int c = 0; c < IN_DIM; ++c) atomicAdd(&yr[c], nrm * x[s * IN_DIM + c]);
        }
    }
    if (t == 0) {
        float nrm = dn * dn;
        #pragma unroll
        for (int c = 0; c < IN_DIM; ++c) atomicAdd(&yr[c], nrm * x[n * IN_DIM + c]);
    }
    __syncthreads();
    if (n == 0) {
        for (int a = t; a < ACTIONS; a += 256) logits[a] = 0.f;
        if (t == 0) *counter = 0u;
    }

    const float4* Wg4 = (const float4*)Wg;    // [IN_DIM][2048]
    const float4* bg4 = (const float4*)bg;    // [2048]
    const float4* lng4 = (const float4*)lng;  // [2048]
    float4 hv[8];
    float s = 0.f, s2 = 0.f;
    #pragma unroll
    for (int k = 0; k < 8; ++k) {
        int j4 = t + k * 256;
        float4 h = bg4[j4];
        #pragma unroll
        for (int c = 0; c < IN_DIM; ++c) {
            float4 w = Wg4[c * (HIDDEN / 4) + j4];
            float yc = yr[c];
            h.x = fmaf(yc, w.x, h.x);
            h.y = fmaf(yc, w.y, h.y);
            h.z = fmaf(yc, w.z, h.z);
            h.w = fmaf(yc, w.w, h.w);
        }
        h.x = fmaxf(h.x, 0.f); h.y = fmaxf(h.y, 0.f);
        h.z = fmaxf(h.z, 0.f); h.w = fmaxf(h.w, 0.f);
        hv[k] = h;
        s  += h.x + h.y + h.z + h.w;
        s2 += h.x * h.x + h.y * h.y + h.z * h.z + h.w * h.w;
    }
    #pragma unroll
    for (int off = 32; off > 0; off >>= 1) { s += __shfl_xor(s, off); s2 += __shfl_xor(s2, off); }
    int wave = t >> 6, lane = t & 63;
    if (lane == 0) { red[wave] = s; red[4 + wave] = s2; }
    __syncthreads();
    float S  = red[0] + red[1] + red[2] + red[3];
    float S2 = red[4] + red[5] + red[6] + red[7];
    float mu = S * (1.f / HIDDEN);
    float var = S2 * (1.f / HIDDEN) - mu * mu;
    float inv = rsqrtf(var + 1e-5f);
    float4* hn4 = (float4*)hn + (size_t)n * (HIDDEN / 4);
    #pragma unroll
    for (int k = 0; k < 8; ++k) {
        int j4 = t + k * 256;
        float4 h = hv[k];
        float4 g = lng4[j4];
        float4 o;
        o.x = (h.x - mu) * inv * g.x;
        o.y = (h.y - mu) * inv * g.y;
        o.z = (h.z - mu) * inv * g.z;
        o.w = (h.w - mu) * inv * g.w;
        hn4[j4] = o;
    }
}

// ---- K2: gemv1. Grid (128, 8): ch = blockIdx.x (64 rows), ct = blockIdx.y.
//      Prefetch 8 W1 rows into regs FIRST, then cheap preamble (sum 81
//      L2-resident hn rows -> gl), then stream the rest (NT tail for L3
//      retention of the W1 head across graph replays).
__global__ __launch_bounds__(256) void gemv1_kernel(const float* __restrict__ lnb,
                                                    const float* __restrict__ hn,
                                                    const float* __restrict__ W1,
                                                    float* __restrict__ partial) {
    const int ch = blockIdx.x;     // 0..127 k chunk (64 rows)
    const int ct = blockIdx.y;     // 0..7   col tile (1024 cols)
    const int row0 = ch * 64;
    const int t = threadIdx.x;

    __shared__ float gred[4][64];
    __shared__ float gl[64];

    const float* pbase = W1 + (size_t)row0 * HIDDEN + ct * 1024 + t * 4;

    // issue first 8 row-loads before the preamble (overlap HBM latency)
    float4 pre[8];
    if (ch >= NT_CH) {
        #pragma unroll
        for (int i = 0; i < 8; ++i) {
            const float* q = pbase + (size_t)i * HIDDEN;
            pre[i].x = __builtin_nontemporal_load(q);
            pre[i].y = __builtin_nontemporal_load(q + 1);
            pre[i].z = __builtin_nontemporal_load(q + 2);
            pre[i].w = __builtin_nontemporal_load(q + 3);
        }
    } else {
        const float4* p = (const float4*)pbase;
        #pragma unroll
        for (int i = 0; i < 8; ++i) pre[i] = p[(size_t)i * (HIDDEN / 4)];
    }

    // cheap preamble: gl = sum_n hn[n][row0+r] + 81*lnb
    {
        const int r = t & 63, grp = t >> 6;
        float a = 0.f;
        #pragma unroll 3
        for (int n = grp; n < N_NODES; n += 4)
            a += hn[(size_t)n * HIDDEN + row0 + r];
        gred[grp][r] = a;
    }
    __syncthreads();
    if (t < 64)
        gl[t] = gred[0][t] + gred[1][t] + gred[2][t] + gred[3][t]
                + (float)N_NODES * lnb[row0 + t];
    __syncthreads();

    float4 acc = make_float4(0.f, 0.f, 0.f, 0.f);
    #pragma unroll
    for (int i = 0; i < 8; ++i) {
        float gi = gl[i];
        acc.x = fmaf(gi, pre[i].x, acc.x);
        acc.y = fmaf(gi, pre[i].y, acc.y);
        acc.z = fmaf(gi, pre[i].z, acc.z);
        acc.w = fmaf(gi, pre[i].w, acc.w);
    }
    if (ch >= NT_CH) {
        #pragma unroll 8
        for (int i = 8; i < 64; ++i) {
            const float* q = pbase + (size_t)i * HIDDEN;
            float4 w;
            w.x = __builtin_nontemporal_load(q);
            w.y = __builtin_nontemporal_load(q + 1);
            w.z = __builtin_nontemporal_load(q + 2);
            w.w = __builtin_nontemporal_load(q + 3);
            float gi = gl[i];
            acc.x = fmaf(gi, w.x, acc.x);
            acc.y = fmaf(gi, w.y, acc.y);
            acc.z = fmaf(gi, w.z, acc.z);
            acc.w = fmaf(gi, w.w, acc.w);
        }
    } else {
        const float4* p = (const float4*)pbase;
        #pragma unroll 8
        for (int i = 8; i < 64; ++i) {
            float4 w = p[(size_t)i * (HIDDEN / 4)];
            float gi = gl[i];
            acc.x = fmaf(gi, w.x, acc.x);
            acc.y = fmaf(gi, w.y, acc.y);
            acc.z = fmaf(gi, w.z, acc.z);
            acc.w = fmaf(gi, w.w, acc.w);
        }
    }
    ((float4*)(partial + (size_t)ch * HIDDEN + ct * 1024))[t] = acc;
}

// ---- K3: gemv2 + fused log-softmax via atomic-only semaphore (no fences).
//      256 blocks x 256. (R13-validated, byte-identical.)
__global__ __launch_bounds__(256) void gemv2_lsm_kernel(const float* __restrict__ partial,
                                                        const float* __restrict__ b1,
                                                        const float* __restrict__ W2,
                                                        const float* __restrict__ b2,
                                                        float* __restrict__ logits,
                                                        unsigned* __restrict__ counter,
                                                        float* __restrict__ out) {
    const int ch = blockIdx.x;     // 0..255, 32 rows each
    const int row0 = ch * 32;
    const int t = threadIdx.x;
    __shared__ float sred[8][32];
    __shared__ float gl[32];
    __shared__ int isLast;

    {
        const int r = t & 31, grp = t >> 5;   // 8 groups
        float a = 0.f;
        #pragma unroll 4
        for (int c = grp; c < 128; c += 8) a += partial[(size_t)c * HIDDEN + row0 + r];
        sred[grp][r] = a;
    }
    __syncthreads();
    if (t < 32) {
        float S = b1[row0 + t];
        #pragma unroll
        for (int gq = 0; gq < 8; ++gq) S += sred[gq][t];
        gl[t] = fmaxf(S, 0.f);
    }
    __syncthreads();

    float s0 = 0.f, s1 = 0.f, s2v = 0.f;
    const bool has2 = (t + 512) < ACTIONS;
    #pragma unroll 4
    for (int i = 0; i < 32; ++i) {
        float gi = gl[i];
        const float* r = W2 + (size_t)(row0 + i) * ACTIONS;
        s0 = fmaf(gi, r[t], s0);
        s1 = fmaf(gi, r[t + 256], s1);
        if (has2) s2v = fmaf(gi, r[t + 512], s2v);
    }
    atomicAdd(&logits[t], s0);
    atomicAdd(&logits[t + 256], s1);
    if (has2) atomicAdd(&logits[t + 512], s2v);

    asm volatile("s_waitcnt vmcnt(0)" ::: "memory");
    __syncthreads();
    if (t == 0) isLast = (atomicAdd(counter, 1u) == 255u) ? 1 : 0;
    __syncthreads();

    if (isLast) {
        float l0 = __hip_atomic_load(&logits[t], __ATOMIC_RELAXED,
                                     __HIP_MEMORY_SCOPE_AGENT) + b2[t];
        float l1 = __hip_atomic_load(&logits[t + 256], __ATOMIC_RELAXED,
                                     __HIP_MEMORY_SCOPE_AGENT) + b2[t + 256];
        float l2 = has2 ? (__hip_atomic_load(&logits[t + 512], __ATOMIC_RELAXED,
                                             __HIP_MEMORY_SCOPE_AGENT) + b2[t + 512])
                        : -INFINITY;
        float m = fmaxf(fmaxf(l0, l1), l2);
        #pragma unroll
        for (int off = 32; off > 0; off >>= 1) m = fmaxf(m, __shfl_xor(m, off));
        if ((t & 63) == 0) sred[0][t >> 6] = m;
        __syncthreads();
        float M = fmaxf(fmaxf(sred[0][0], sred[0][1]), fmaxf(sred[0][2], sred[0][3]));
        __syncthreads();
        float e = __expf(l0 - M) + __expf(l1 - M) + (has2 ? __expf(l2 - M) : 0.f);
        #pragma unroll
        for (int off = 32; off > 0; off >>= 1) e += __shfl_xor(e, off);
        if ((t & 63) == 0) sred[0][t >> 6] = e;
        __syncthreads();
        float Se = sred[0][0] + sred[0][1] + sred[0][2] + sred[0][3];
        float L = logf(Se);
        out[t] = l0 - M - L;
        out[t + 256] = l1 - M - L;
        if (has2) out[t + 512] = l2 - M - L;
    }
}

extern "C" void kernel_launch(void* const* d_in, const int* in_sizes, int n_in,
                              void* d_out, int out_size, void* d_ws, size_t ws_size,
                              hipStream_t stream) {
    const float* x    = (const float*)d_in[0];
    const int*   ei   = (const int*)  d_in[1];
    const float* Wg   = (const float*)d_in[2];
    const float* bg   = (const float*)d_in[3];
    const float* lng  = (const float*)d_in[4];
    const float* lnb  = (const float*)d_in[5];
    const float* W1   = (const float*)d_in[6];
    const float* b1   = (const float*)d_in[7];
    const float* W2   = (const float*)d_in[8];
    const float* b2   = (const float*)d_in[9];
    float* out = (float*)d_out;

    float* ws = (float*)d_ws;
    float* logits     = ws;                       // 1024 (729 used)
    unsigned* counter = (unsigned*)(ws + 1024);   // 1 (padded)
    float* hn         = ws + 4096;                // 81*8192 = 663552
    float* partial    = ws + 4096 + 663552;       // 128*8192 = 1048576

    k1_kernel<<<N_NODES, 256, 0, stream>>>(x, ei, Wg, bg, lng, hn, logits, counter);
    gemv1_kernel<<<dim3(128, 8), 256, 0, stream>>>(lnb, hn, W1, partial);
    gemv2_lsm_kernel<<<256, 256, 0, stream>>>(partial, b1, W2, b2, logits, counter, out);
}

// Round 17
// 89.706 us; speedup vs baseline: 1.1048x; 1.0396x over previous
//
#include <hip/hip_runtime.h>
#include <math.h>

#define N_NODES 81
#define N_EDGES 1620
#define IN_DIM 10
#define HIDDEN 8192
#define ACTIONS 729
#define NT_CH 92   // k-chunks >= this streamed non-temporally (L3 retention)

// ---- K1: edge aggregation -> yr[81][10]; LN stats (mu, inv) per node.
//      81 blocks x 256. Block 0 zeroes logits + counter.
__global__ __launch_bounds__(256) void stats_kernel(const float* __restrict__ x,
                                                    const int* __restrict__ ei,
                                                    const float* __restrict__ Wg,
                                                    const float* __restrict__ bg,
                                                    float* __restrict__ yr_all,
                                                    float* __restrict__ stats,
                                                    float* __restrict__ logits,
                                                    unsigned* __restrict__ counter) {
    const int n = blockIdx.x;
    const int t = threadIdx.x;
    __shared__ float deg[N_NODES];
    __shared__ float yr[IN_DIM];
    __shared__ float red[8];

    if (t < N_NODES) deg[t] = 1.0f;           // self-loop
    if (t < IN_DIM) yr[t] = 0.0f;
    __syncthreads();
    for (int e = t; e < N_EDGES; e += 256) atomicAdd(&deg[ei[N_EDGES + e]], 1.0f);
    __syncthreads();
    if (t < N_NODES) deg[t] = rsqrtf(deg[t]); // deg >= 1 always
    __syncthreads();
    const float dn = deg[n];
    for (int e = t; e < N_EDGES; e += 256) {
        if (ei[N_EDGES + e] == n) {
            int s = ei[e];
            float nrm = deg[s] * dn;
            #pragma unroll
            for (int c = 0; c < IN_DIM; ++c) atomicAdd(&yr[c], nrm * x[s * IN_DIM + c]);
        }
    }
    if (t == 0) {
        float nrm = dn * dn;
        #pragma unroll
        for (int c = 0; c < IN_DIM; ++c) atomicAdd(&yr[c], nrm * x[n * IN_DIM + c]);
    }
    __syncthreads();
    if (t < IN_DIM) yr_all[n * IN_DIM + t] = yr[t];
    if (n == 0) {
        for (int a = t; a < ACTIONS; a += 256) logits[a] = 0.f;
        if (t == 0) *counter = 0u;
    }

    const float4* Wg4 = (const float4*)Wg;    // [IN_DIM][2048]
    const float4* bg4 = (const float4*)bg;    // [2048]
    float s = 0.f, s2 = 0.f;
    #pragma unroll
    for (int k = 0; k < 8; ++k) {
        int j4 = t + k * 256;
        float4 h = bg4[j4];
        #pragma unroll
        for (int c = 0; c < IN_DIM; ++c) {
            float4 w = Wg4[c * (HIDDEN / 4) + j4];
            float yc = yr[c];
            h.x = fmaf(yc, w.x, h.x);
            h.y = fmaf(yc, w.y, h.y);
            h.z = fmaf(yc, w.z, h.z);
            h.w = fmaf(yc, w.w, h.w);
        }
        h.x = fmaxf(h.x, 0.f); h.y = fmaxf(h.y, 0.f);
        h.z = fmaxf(h.z, 0.f); h.w = fmaxf(h.w, 0.f);
        s  += h.x + h.y + h.z + h.w;
        s2 += h.x * h.x + h.y * h.y + h.z * h.z + h.w * h.w;
    }
    #pragma unroll
    for (int off = 32; off > 0; off >>= 1) { s += __shfl_xor(s, off); s2 += __shfl_xor(s2, off); }
    int wave = t >> 6, lane = t & 63;
    if (lane == 0) { red[wave] = s; red[4 + wave] = s2; }
    __syncthreads();
    if (t == 0) {
        float S  = red[0] + red[1] + red[2] + red[3];
        float S2 = red[4] + red[5] + red[6] + red[7];
        float mu = S * (1.f / HIDDEN);
        float var = S2 * (1.f / HIDDEN) - mu * mu;
        stats[2 * n]     = mu;
        stats[2 * n + 1] = rsqrtf(var + 1e-5f);
    }
}

// ---- K2: gemv1. Grid (128, 8): blockIdx.x = ch (k chunk, 64 rows),
//      blockIdx.y = ct (col tile). XCD = ch % 8 so all 8 column-tiles of one
//      2 MB row-chunk land on the same XCD. NT tail (ch >= NT_CH) keeps the
//      W1 head Infinity-Cache resident across graph replays.
__global__ __launch_bounds__(256) void gemv1_kernel(const float* __restrict__ Wg,
                                                    const float* __restrict__ bg,
                                                    const float* __restrict__ lng,
                                                    const float* __restrict__ lnb,
                                                    const float* __restrict__ yr_all,
                                                    const float* __restrict__ stats,
                                                    const float* __restrict__ W1,
                                                    float* __restrict__ partial) {
    const int ch = blockIdx.x;     // 0..127 k chunk (64 rows)  [XCD = ch%8]
    const int ct = blockIdx.y;     // 0..7   col tile (1024 cols)
    const int row0 = ch * 64;
    const int t = threadIdx.x;

    __shared__ float syr[N_NODES * IN_DIM];   // 810
    __shared__ float sstat[2 * N_NODES];      // 162
    __shared__ float sw[IN_DIM][64];          // Wg slice
    __shared__ float gred[4][64];
    __shared__ float gl[64];

    for (int i = t; i < N_NODES * IN_DIM; i += 256) syr[i] = yr_all[i];
    for (int i = t; i < 2 * N_NODES; i += 256) sstat[i] = stats[i];
    if (t < 64) {
        #pragma unroll
        for (int c = 0; c < IN_DIM; ++c) sw[c][t] = Wg[c * HIDDEN + row0 + t];
    }
    __syncthreads();

    {
        const int r = t & 63, grp = t >> 6;
        const float bgv = bg[row0 + r];
        float acc = 0.f;
        for (int n = grp; n < N_NODES; n += 4) {
            float h = bgv;
            #pragma unroll
            for (int c = 0; c < IN_DIM; ++c) h = fmaf(syr[n * IN_DIM + c], sw[c][r], h);
            h = fmaxf(h, 0.f);
            acc += (h - sstat[2 * n]) * sstat[2 * n + 1];
        }
        gred[grp][r] = acc;
    }
    __syncthreads();
    if (t < 64)
        gl[t] = (gred[0][t] + gred[1][t] + gred[2][t] + gred[3][t]) * lng[row0 + t]
                + (float)N_NODES * lnb[row0 + t];
    __syncthreads();

    float4 acc = make_float4(0.f, 0.f, 0.f, 0.f);
    const float* pbase = W1 + (size_t)row0 * HIDDEN + ct * 1024 + t * 4;
    if (ch >= NT_CH) {
        #pragma unroll 8
        for (int i = 0; i < 64; ++i) {
            const float* q = pbase + (size_t)i * HIDDEN;
            float4 w;
            w.x = __builtin_nontemporal_load(q);
            w.y = __builtin_nontemporal_load(q + 1);
            w.z = __builtin_nontemporal_load(q + 2);
            w.w = __builtin_nontemporal_load(q + 3);
            float gi = gl[i];
            acc.x = fmaf(gi, w.x, acc.x);
            acc.y = fmaf(gi, w.y, acc.y);
            acc.z = fmaf(gi, w.z, acc.z);
            acc.w = fmaf(gi, w.w, acc.w);
        }
    } else {
        const float4* p = (const float4*)(pbase);
        #pragma unroll 8
        for (int i = 0; i < 64; ++i) {
            float4 w = p[(size_t)i * (HIDDEN / 4)];
            float gi = gl[i];
            acc.x = fmaf(gi, w.x, acc.x);
            acc.y = fmaf(gi, w.y, acc.y);
            acc.z = fmaf(gi, w.z, acc.z);
            acc.w = fmaf(gi, w.w, acc.w);
        }
    }
    ((float4*)(partial + (size_t)ch * HIDDEN + ct * 1024))[t] = acc;
}

// ---- K3: gemv2 + fused log-softmax via atomic-only semaphore (no fences).
//      256 blocks x 256.
__global__ __launch_bounds__(256) void gemv2_lsm_kernel(const float* __restrict__ partial,
                                                        const float* __restrict__ b1,
                                                        const float* __restrict__ W2,
                                                        const float* __restrict__ b2,
                                                        float* __restrict__ logits,
                                                        unsigned* __restrict__ counter,
                                                        float* __restrict__ out) {
    const int ch = blockIdx.x;     // 0..255, 32 rows each
    const int row0 = ch * 32;
    const int t = threadIdx.x;
    __shared__ float sred[8][32];
    __shared__ float gl[32];
    __shared__ int isLast;

    {
        const int r = t & 31, grp = t >> 5;   // 8 groups
        float a = 0.f;
        #pragma unroll 4
        for (int c = grp; c < 128; c += 8) a += partial[(size_t)c * HIDDEN + row0 + r];
        sred[grp][r] = a;
    }
    __syncthreads();
    if (t < 32) {
        float S = b1[row0 + t];
        #pragma unroll
        for (int gq = 0; gq < 8; ++gq) S += sred[gq][t];
        gl[t] = fmaxf(S, 0.f);
    }
    __syncthreads();

    float s0 = 0.f, s1 = 0.f, s2v = 0.f;
    const bool has2 = (t + 512) < ACTIONS;
    #pragma unroll 4
    for (int i = 0; i < 32; ++i) {
        float gi = gl[i];
        const float* r = W2 + (size_t)(row0 + i) * ACTIONS;
        s0 = fmaf(gi, r[t], s0);
        s1 = fmaf(gi, r[t + 256], s1);
        if (has2) s2v = fmaf(gi, r[t + 512], s2v);
    }
    atomicAdd(&logits[t], s0);
    atomicAdd(&logits[t + 256], s1);
    if (has2) atomicAdd(&logits[t + 512], s2v);

    asm volatile("s_waitcnt vmcnt(0)" ::: "memory");
    __syncthreads();
    if (t == 0) isLast = (atomicAdd(counter, 1u) == 255u) ? 1 : 0;
    __syncthreads();

    if (isLast) {
        float l0 = __hip_atomic_load(&logits[t], __ATOMIC_RELAXED,
                                     __HIP_MEMORY_SCOPE_AGENT) + b2[t];
        float l1 = __hip_atomic_load(&logits[t + 256], __ATOMIC_RELAXED,
                                     __HIP_MEMORY_SCOPE_AGENT) + b2[t + 256];
        float l2 = has2 ? (__hip_atomic_load(&logits[t + 512], __ATOMIC_RELAXED,
                                             __HIP_MEMORY_SCOPE_AGENT) + b2[t + 512])
                        : -INFINITY;
        float m = fmaxf(fmaxf(l0, l1), l2);
        #pragma unroll
        for (int off = 32; off > 0; off >>= 1) m = fmaxf(m, __shfl_xor(m, off));
        if ((t & 63) == 0) sred[0][t >> 6] = m;
        __syncthreads();
        float M = fmaxf(fmaxf(sred[0][0], sred[0][1]), fmaxf(sred[0][2], sred[0][3]));
        __syncthreads();
        float e = __expf(l0 - M) + __expf(l1 - M) + (has2 ? __expf(l2 - M) : 0.f);
        #pragma unroll
        for (int off = 32; off > 0; off >>= 1) e += __shfl_xor(e, off);
        if ((t & 63) == 0) sred[0][t >> 6] = e;
        __syncthreads();
        float Se = sred[0][0] + sred[0][1] + sred[0][2] + sred[0][3];
        float L = logf(Se);
        out[t] = l0 - M - L;
        out[t + 256] = l1 - M - L;
        if (has2) out[t + 512] = l2 - M - L;
    }
}

extern "C" void kernel_launch(void* const* d_in, const int* in_sizes, int n_in,
                              void* d_out, int out_size, void* d_ws, size_t ws_size,
                              hipStream_t stream) {
    const float* x    = (const float*)d_in[0];
    const int*   ei   = (const int*)  d_in[1];
    const float* Wg   = (const float*)d_in[2];
    const float* bg   = (const float*)d_in[3];
    const float* lng  = (const float*)d_in[4];
    const float* lnb  = (const float*)d_in[5];
    const float* W1   = (const float*)d_in[6];
    const float* b1   = (const float*)d_in[7];
    const float* W2   = (const float*)d_in[8];
    const float* b2   = (const float*)d_in[9];
    float* out = (float*)d_out;

    float* ws = (float*)d_ws;
    float* logits    = ws;                      // 1024 (729 used)
    unsigned* counter = (unsigned*)(ws + 1024); // 1 (padded)
    float* stats   = ws + 1088;                 // 162
    float* yr_all  = ws + 1280;                 // 810
    float* partial = ws + 4096;                 // 128*8192 = 1048576 (16B aligned)

    stats_kernel<<<N_NODES, 256, 0, stream>>>(x, ei, Wg, bg, yr_all, stats, logits, counter);
    gemv1_kernel<<<dim3(128, 8), 256, 0, stream>>>(Wg, bg, lng, lnb, yr_all, stats, W1, partial);
    gemv2_lsm_kernel<<<256, 256, 0, stream>>>(partial, b1, W2, b2, logits, counter, out);
}